// Round 14
// baseline (568.192 us; speedup 1.0000x reference)
//
#include <hip/hip_runtime.h>

// ---------------- problem constants ----------------
#define N_NODES   20000
#define N_EDGES   640000
#define CF        313      // FEAT + NUM_SEM
#define KC        320      // child K padded (313 -> 320), 10 ksteps
#define ROWB      640      // child LDS A-tile row stride bytes

typedef __attribute__((ext_vector_type(8))) short short8;
typedef __attribute__((ext_vector_type(4))) float f32x4;
typedef __attribute__((ext_vector_type(4))) unsigned short u16x4;
typedef float f32x4u __attribute__((ext_vector_type(4), aligned(4)));
typedef _Float16 h2 __attribute__((ext_vector_type(2)));

static __device__ __forceinline__ unsigned short f2bf(float f) {
    unsigned u = __float_as_uint(f);
    u = u + 0x7FFFu + ((u >> 16) & 1u);   // RNE
    return (unsigned short)(u >> 16);
}
static __device__ __forceinline__ int pkh(float a, float b) {
    h2 h; h.x = (_Float16)a; h.y = (_Float16)b;
    return __builtin_bit_cast(int, h);
}
static __device__ __forceinline__ h2 bch(int v) { return __builtin_bit_cast(h2, v); }
static __device__ __forceinline__ float dot2f(h2 a, h2 b, float c) {
    return __builtin_amdgcn_fdot2(a, b, c, false);   // v_dot2_f32_f16
}

// ---------------- fused setup: weight prep | edge hist ----------------
__global__ void setup_kernel(const float* __restrict__ Wc,
                             const float* __restrict__ We0,
                             const float* __restrict__ We1,
                             const int* __restrict__ eidx,
                             unsigned short* __restrict__ WcT,
                             unsigned short* __restrict__ Wab0,
                             unsigned short* __restrict__ Wab1,
                             unsigned* __restrict__ hist) {
    const int b = blockIdx.x, tid = threadIdx.x;
    if (b < 416) {
        int g = b * 256 + tid;                    // 106496 = 416*256
        if (g < 128 * KC) {
            int n = g / KC, k = g % KC;
            WcT[g] = f2bf(k < CF ? Wc[k * 128 + n] : 0.f);
        } else if (g < 128 * KC + 32768) {
            int h = g - 128 * KC;
            int n = h >> 7, k = h & 127;
            Wab0[h] = f2bf(n < 128 ? We0[k * 128 + n] : We0[(128 + k) * 128 + (n - 128)]);
        } else {
            int h = g - 128 * KC - 32768;
            int n = h >> 7, k = h & 127;
            Wab1[h] = f2bf(n < 128 ? We1[k * 128 + n] : We1[(128 + k) * 128 + (n - 128)]);
        }
    } else {
        int e = (b - 416) * 256 + tid;
        if (e < N_EDGES) atomicAdd(hist + eidx[2 * e], 1u);
    }
}

// ---------------- scan (exclusive prefix) + parent/queue zero ---------------
__global__ void scan_kernel(const unsigned* __restrict__ hist,
                            unsigned* __restrict__ cursor,
                            unsigned* __restrict__ cstart,
                            unsigned* __restrict__ parent,
                            unsigned* __restrict__ qctr) {
    __shared__ unsigned part[1024];
    int t = threadIdx.x;
    if (t < 384) parent[t] = 0;                   // runs before child_ab
    if (t == 0) { qctr[0] = 0; qctr[1] = 0; }     // edge_pass work queues
    unsigned loc[20];
    unsigned s = 0;
    int base = t * 20;
    if (t < 1000) {
        #pragma unroll
        for (int i = 0; i < 20; ++i) { loc[i] = hist[base + i]; s += loc[i]; }
    }
    part[t] = s;
    __syncthreads();
    for (int off = 1; off < 1024; off <<= 1) {
        unsigned u = (t >= off) ? part[t - off] : 0u;
        __syncthreads();
        part[t] += u;
        __syncthreads();
    }
    if (t < 1000) {
        unsigned run = part[t] - s;
        #pragma unroll
        for (int i = 0; i < 20; ++i) {
            cursor[base + i] = run;
            cstart[base + i] = run;
            run += loc[i];
        }
    }
}

// 32B record per sorted edge: {dst, ef01, ef23, ef45, ef67, ef89, efAB, pad}
__global__ void scatter_kernel(const int* __restrict__ eidx,
                               const float* __restrict__ onehot,
                               const float* __restrict__ efeat,
                               unsigned* __restrict__ cursor,
                               int4* __restrict__ es) {
    int e = blockIdx.x * 256 + threadIdx.x;
    if (e >= N_EDGES) return;
    int2 sd = ((const int2*)eidx)[e];
    unsigned pos = atomicAdd(cursor + sd.x, 1u);
    float4 oh = *(const float4*)(onehot + 4 * (size_t)e);
    float4 ea = *(const float4*)(efeat + 8 * (size_t)e);
    float4 eb = *(const float4*)(efeat + 8 * (size_t)e + 4);
    int4 w0, w1;
    w0.x = sd.y;
    w0.y = pkh(oh.x, oh.y); w0.z = pkh(oh.z, oh.w); w0.w = pkh(ea.x, ea.y);
    w1.x = pkh(ea.z, ea.w); w1.y = pkh(eb.x, eb.y); w1.z = pkh(eb.z, eb.w);
    w1.w = 0;
    es[2 * (size_t)pos]     = w0;
    es[2 * (size_t)pos + 1] = w1;
}

// ---------------- fused child encoder + A|B GEMM ----------------------------
// phase 1: h = relu(cf @ Wc + bc) * exists  (h kept in LDS, colmax -> parent)
// phase 2: A = h@Wsrc + be (f32), B = h@Wdst (bf16) from the same 64-row tile
__global__ __launch_bounds__(256)
void child_ab(const float* __restrict__ cf,             // [20000][313] f32
              const float* __restrict__ exists,
              const unsigned short* __restrict__ WcT,   // [128][320] bf16
              const float* __restrict__ bc,
              const unsigned short* __restrict__ Wab,   // [256][128] bf16
              const float* __restrict__ be,
              float* __restrict__ Afl,                  // [20000][128] f32
              unsigned short* __restrict__ Bbf,         // [20000][128] bf16
              unsigned int* __restrict__ pmax) {        // [128] colmax
    __shared__ __align__(16) unsigned char Alds[64 * ROWB];   // 40 KB
    __shared__ __align__(16) unsigned char Hlds[64 * 256];    // 16 KB

    const int tid  = threadIdx.x;
    const int lane = tid & 63;
    const int wave = tid >> 6;
    const int row0 = blockIdx.x * 64;

    // ======== phase 1: child ========
    const int n0c = wave * 32;
    short8 bfrag[10][2];
    {
        int col  = n0c + (lane & 15);
        int krow = (lane >> 4) * 8;
        #pragma unroll
        for (int ks = 0; ks < 10; ++ks)
            #pragma unroll
            for (int nt = 0; nt < 2; ++nt)
                bfrag[ks][nt] = *(const short8*)(WcT + (col + nt * 16) * KC + ks * 32 + krow);
    }
    float bvc[2];
    bvc[0] = bc[n0c + (lane & 15)];
    bvc[1] = bc[n0c + 16 + (lane & 15)];

    {   // stage cf tile (vectorized 4B-aligned loads)
        int r = tid >> 2, p = tid & 3;
        int node = row0 + r;
        bool valid = node < N_NODES;
        const float* g = cf + (size_t)node * CF;
        unsigned rbase = r * ROWB;
        unsigned sw = (r & 7) << 4;
        #pragma unroll
        for (int i = 0; i < 10; ++i) {
            int c = p + i * 4;                 // chunk 0..39, 8 bf16 each
            short8 v = {};
            if (valid) {
                if (c < 39) {
                    f32x4u a0 = *(const f32x4u*)(g + c * 8);
                    f32x4u a1 = *(const f32x4u*)(g + c * 8 + 4);
                    v[0] = (short)f2bf(a0.x); v[1] = (short)f2bf(a0.y);
                    v[2] = (short)f2bf(a0.z); v[3] = (short)f2bf(a0.w);
                    v[4] = (short)f2bf(a1.x); v[5] = (short)f2bf(a1.y);
                    v[6] = (short)f2bf(a1.z); v[7] = (short)f2bf(a1.w);
                } else {
                    v[0] = (short)f2bf(g[312]);   // k=312 only (313..319 pad)
                }
            }
            *(short8*)(Alds + ((rbase + c * 16) ^ sw)) = v;
        }
    }
    __syncthreads();

    f32x4 acc[4][2] = {};
    {
        int arow = lane & 15;
        unsigned kb = (lane >> 4) * 16;
        #pragma unroll
        for (int ks = 0; ks < 10; ++ks)
            #pragma unroll
            for (int mt = 0; mt < 4; ++mt) {
                int row = mt * 16 + arow;
                short8 a = *(const short8*)(Alds + (((unsigned)row * ROWB + ks * 64 + kb) ^ ((row & 7) << 4)));
                acc[mt][0] = __builtin_amdgcn_mfma_f32_16x16x32_bf16(a, bfrag[ks][0], acc[mt][0], 0, 0, 0);
                acc[mt][1] = __builtin_amdgcn_mfma_f32_16x16x32_bf16(a, bfrag[ks][1], acc[mt][1], 0, 0, 0);
            }
    }

    {   // epilogue: h -> Hlds (swizzled bf16) + column max
        int rb = (lane >> 4) * 4;
        #pragma unroll
        for (int nt = 0; nt < 2; ++nt) {
            int col = n0c + nt * 16 + (lane & 15);
            float m = 0.f;
            #pragma unroll
            for (int mt = 0; mt < 4; ++mt)
                #pragma unroll
                for (int j = 0; j < 4; ++j) {
                    int r = mt * 16 + rb + j;
                    int node = row0 + r;
                    float v = 0.f;
                    if (node < N_NODES)
                        v = fmaxf(acc[mt][nt][j] + bvc[nt], 0.f) * exists[node];
                    *(unsigned short*)(Hlds + (((unsigned)r * 256 + col * 2) ^ ((r & 7) << 4))) = f2bf(v);
                    m = fmaxf(m, v);
                }
            m = fmaxf(m, __shfl_xor(m, 16));
            m = fmaxf(m, __shfl_xor(m, 32));
            if ((lane >> 4) == 0)
                atomicMax(pmax + col, __float_as_uint(m));
        }
    }
    __syncthreads();

    // ======== phase 2: A|B from Hlds ========
    const int n0 = wave * 64;
    const int krow = (lane >> 4) * 8;
    short8 bfrag2[4][4];
    {
        int colb = n0 + (lane & 15);
        #pragma unroll
        for (int ks = 0; ks < 4; ++ks)
            #pragma unroll
            for (int nt = 0; nt < 4; ++nt)
                bfrag2[ks][nt] = *(const short8*)(Wab + (colb + nt * 16) * 128 + ks * 32 + krow);
    }

    f32x4 acc2[4][4] = {};
    #pragma unroll
    for (int ks = 0; ks < 4; ++ks)
        #pragma unroll
        for (int mt = 0; mt < 4; ++mt) {
            int r = mt * 16 + (lane & 15);
            short8 a = *(const short8*)(Hlds + (((unsigned)r * 256 + ks * 64 + krow * 2) ^ ((r & 7) << 4)));
            #pragma unroll
            for (int nt = 0; nt < 4; ++nt)
                acc2[mt][nt] = __builtin_amdgcn_mfma_f32_16x16x32_bf16(a, bfrag2[ks][nt], acc2[mt][nt], 0, 0, 0);
        }

    {
        int rb = (lane >> 4) * 4;
        #pragma unroll
        for (int nt = 0; nt < 4; ++nt) {
            int col = n0 + nt * 16 + (lane & 15);        // 0..255
            float badd = (col < 128) ? be[col] : 0.f;
            #pragma unroll
            for (int mt = 0; mt < 4; ++mt)
                #pragma unroll
                for (int j = 0; j < 4; ++j) {
                    int row = row0 + mt * 16 + rb + j;
                    if (row < N_NODES) {
                        float v = acc2[mt][nt][j] + badd;
                        if (col < 128) Afl[(size_t)row * 128 + col] = v;
                        else           Bbf[(size_t)row * 128 + col - 128] = f2bf(v);
                    }
                }
        }
    }
}

// ---------------- A|B node GEMM (layer 2): 32-row tiles, 625 blocks ---------
__global__ __launch_bounds__(256)
void gemmAB(const unsigned short* __restrict__ hbf,
            const unsigned short* __restrict__ WT,    // [256][128] bf16
            const float* __restrict__ bias,
            float* __restrict__ Afl,
            unsigned short* __restrict__ Bbf) {
    const int tid  = threadIdx.x;
    const int lane = tid & 63;
    const int wave = tid >> 6;
    const int n0   = wave * 64;
    const int row0 = blockIdx.x * 32;       // 625 * 32 = 20000 exactly
    const int krow = (lane >> 4) * 8;

    short8 bfrag[4][4];
    {
        int colb = n0 + (lane & 15);
        #pragma unroll
        for (int ks = 0; ks < 4; ++ks)
            #pragma unroll
            for (int nt = 0; nt < 4; ++nt)
                bfrag[ks][nt] = *(const short8*)(WT + (colb + nt * 16) * 128 + ks * 32 + krow);
    }

    f32x4 acc[2][4] = {};
    #pragma unroll
    for (int ks = 0; ks < 4; ++ks)
        #pragma unroll
        for (int mt = 0; mt < 2; ++mt) {
            int row = row0 + mt * 16 + (lane & 15);
            short8 a = *(const short8*)(hbf + (size_t)row * 128 + ks * 32 + krow);
            #pragma unroll
            for (int nt = 0; nt < 4; ++nt)
                acc[mt][nt] = __builtin_amdgcn_mfma_f32_16x16x32_bf16(a, bfrag[ks][nt], acc[mt][nt], 0, 0, 0);
        }

    {
        int rb = (lane >> 4) * 4;
        #pragma unroll
        for (int nt = 0; nt < 4; ++nt) {
            int col = n0 + nt * 16 + (lane & 15);
            float badd = (col < 128) ? bias[col] : 0.f;
            #pragma unroll
            for (int mt = 0; mt < 2; ++mt)
                #pragma unroll
                for (int j = 0; j < 4; ++j) {
                    int row = row0 + mt * 16 + rb + j;
                    float v = acc[mt][nt][j] + badd;
                    if (col < 128) Afl[(size_t)row * 128 + col] = v;
                    else           Bbf[(size_t)row * 128 + col - 128] = f2bf(v);
                }
        }
    }
}

// ---------------- edge pass v10: dynamic queue, r7 rings per src ------------
// h[s] = relu(A[s] + max_e(B[dst_e] + ef_e @ Wef)). Each 32-lane group pops
// src ids from a global counter (perfect dynamic balance, one resident round).
__global__ __launch_bounds__(256)
void edge_pass(const unsigned short* __restrict__ Bbf,  // [20000][128] bf16
               const float* __restrict__ Afl,           // [20000][128] f32
               const int4* __restrict__ es,             // 2 int4 per sorted edge
               const float* __restrict__ Wef,           // [12][128] f32
               const unsigned* __restrict__ cstart,     // [20000] seg start
               const unsigned* __restrict__ hist,       // [20000] seg count
               unsigned* __restrict__ qctr,             // work-queue counter
               unsigned short* __restrict__ hbf,        // out h bf16
               unsigned* __restrict__ pslice) {         // [128] colmax f32-bits
    __shared__ unsigned cmax[128];
    const int tid = threadIdx.x;
    if (tid < 128) cmax[tid] = 0;
    __syncthreads();

    const int c0 = (tid & 31) * 4;

    h2 wf[6][4];
    #pragma unroll
    for (int kp = 0; kp < 6; ++kp)
        #pragma unroll
        for (int j = 0; j < 4; ++j) {
            h2 w;
            w.x = (_Float16)Wef[(2 * kp) * 128 + c0 + j];
            w.y = (_Float16)Wef[(2 * kp + 1) * 128 + c0 + j];
            wf[kp][j] = w;
        }

    for (;;) {
        unsigned s;
        if ((tid & 31) == 0) s = atomicAdd(qctr, 1u);
        s = (unsigned)__shfl((int)s, (int)(threadIdx.x & 32));  // group leader
        if (s >= N_NODES) break;

        f32x4 a = *(const f32x4*)(Afl + (size_t)s * 128 + c0);
        float m0 = -1e30f, m1 = -1e30f, m2 = -1e30f, m3 = -1e30f;
        const unsigned cnt = hist[s];
        if (cnt) {
            const unsigned last = cnt - 1;
            const unsigned cb = cstart[s] * 32u;          // byte offset into es
            const char* esb = (const char*)es;
            const unsigned short* bbase = Bbf + c0;

            unsigned dstv[12];
            int4 ra[3], rb[3];
            u16x4 bv[6];

            #pragma unroll
            for (int k = 0; k < 12; ++k)
                dstv[k] = *(const unsigned*)(esb + cb + min((unsigned)k, last) * 32u);
            #pragma unroll
            for (int k = 0; k < 3; ++k) {
                const int4* q = (const int4*)(esb + cb + min((unsigned)k, last) * 32u);
                ra[k] = q[0]; rb[k] = q[1];
            }
            #pragma unroll
            for (int k = 0; k < 6; ++k)
                bv[k] = *(const u16x4*)(bbase + (size_t)dstv[k] * 128);

            const unsigned niter = (cnt + 11) / 12;
            for (unsigned it = 0; it < niter; ++it) {
                const unsigned jb = it * 12;
                #pragma unroll
                for (int u = 0; u < 12; ++u) {
                    int4 RA = ra[u % 3], RB = rb[u % 3];
                    u16x4 B = bv[u % 6];
                    h2 e0 = bch(RA.y), e1 = bch(RA.z), e2 = bch(RA.w);
                    h2 e3 = bch(RB.x), e4 = bch(RB.y), e5 = bch(RB.z);

                    float x0 = __uint_as_float(((unsigned)(unsigned short)B[0]) << 16);
                    float x1 = __uint_as_float(((unsigned)(unsigned short)B[1]) << 16);
                    float x2 = __uint_as_float(((unsigned)(unsigned short)B[2]) << 16);
                    float x3 = __uint_as_float(((unsigned)(unsigned short)B[3]) << 16);
                    x0 = dot2f(e0, wf[0][0], x0); x1 = dot2f(e0, wf[0][1], x1);
                    x2 = dot2f(e0, wf[0][2], x2); x3 = dot2f(e0, wf[0][3], x3);
                    x0 = dot2f(e1, wf[1][0], x0); x1 = dot2f(e1, wf[1][1], x1);
                    x2 = dot2f(e1, wf[1][2], x2); x3 = dot2f(e1, wf[1][3], x3);
                    x0 = dot2f(e2, wf[2][0], x0); x1 = dot2f(e2, wf[2][1], x1);
                    x2 = dot2f(e2, wf[2][2], x2); x3 = dot2f(e2, wf[2][3], x3);
                    x0 = dot2f(e3, wf[3][0], x0); x1 = dot2f(e3, wf[3][1], x1);
                    x2 = dot2f(e3, wf[3][2], x2); x3 = dot2f(e3, wf[3][3], x3);
                    x0 = dot2f(e4, wf[4][0], x0); x1 = dot2f(e4, wf[4][1], x1);
                    x2 = dot2f(e4, wf[4][2], x2); x3 = dot2f(e4, wf[4][3], x3);
                    x0 = dot2f(e5, wf[5][0], x0); x1 = dot2f(e5, wf[5][1], x1);
                    x2 = dot2f(e5, wf[5][2], x2); x3 = dot2f(e5, wf[5][3], x3);
                    m0 = fmaxf(m0, x0); m1 = fmaxf(m1, x1);
                    m2 = fmaxf(m2, x2); m3 = fmaxf(m3, x3);

                    // ---- ring refills (all clamped; duplicates idempotent) ----
                    unsigned jd = min(jb + u + 12u, last);
                    dstv[u] = *(const unsigned*)(esb + cb + jd * 32u);
                    unsigned jr = min(jb + u + 3u, last);
                    const int4* q = (const int4*)(esb + cb + jr * 32u);
                    ra[u % 3] = q[0]; rb[u % 3] = q[1];
                    bv[u % 6] = *(const u16x4*)(bbase + (size_t)dstv[(u + 6) % 12] * 128);
                }
            }
        }

        float h0 = fmaxf(a.x + m0, 0.f), h1 = fmaxf(a.y + m1, 0.f);
        float h2v = fmaxf(a.z + m2, 0.f), h3 = fmaxf(a.w + m3, 0.f);

        unsigned lo = (unsigned)f2bf(h0) | ((unsigned)f2bf(h1) << 16);
        unsigned hi = (unsigned)f2bf(h2v) | ((unsigned)f2bf(h3) << 16);
        *(uint2*)(hbf + (size_t)s * 128 + c0) = make_uint2(lo, hi);

        atomicMax(&cmax[c0],     __float_as_uint(h0));
        atomicMax(&cmax[c0 + 1], __float_as_uint(h1));
        atomicMax(&cmax[c0 + 2], __float_as_uint(h2v));
        atomicMax(&cmax[c0 + 3], __float_as_uint(h3));
    }
    __syncthreads();
    if (tid < 128) atomicMax(pslice + tid, cmax[tid]);
}

// ---------------- final: out = relu(parent @ Wp + bp), 16 blocks ------------
__global__ void final_gemm(const float* __restrict__ parent,
                           const float* __restrict__ Wp,
                           const float* __restrict__ bp,
                           float* __restrict__ out) {
    __shared__ float p[384];
    __shared__ float red[256];
    int t = threadIdx.x;
    for (int i = t; i < 384; i += 256) p[i] = parent[i];
    __syncthreads();
    int col = blockIdx.x * 16 + (t & 15);       // 16 blocks x 16 cols
    int kc  = t >> 4;                           // 16 k-slices x 24
    float s = 0.f;
    for (int k = kc * 24; k < kc * 24 + 24; ++k) s += p[k] * Wp[k * 256 + col];
    red[t] = s;
    __syncthreads();
    #pragma unroll
    for (int off = 8; off >= 1; off >>= 1) {
        if (kc < off) red[t] += red[t + off * 16];
        __syncthreads();
    }
    if (t < 16) out[col] = fmaxf(red[t] + bp[col], 0.f);
}

// ---------------- launch ----------------------------------------------------
extern "C" void kernel_launch(void* const* d_in, const int* in_sizes, int n_in,
                              void* d_out, int out_size, void* d_ws, size_t ws_size,
                              hipStream_t stream) {
    const float* child_feats  = (const float*)d_in[0];
    const float* child_exists = (const float*)d_in[1];
    const float* onehot       = (const float*)d_in[2];
    const float* efeat        = (const float*)d_in[3];
    const int*   eidx         = (const int*)d_in[4];
    const float* Wc  = (const float*)d_in[5];
    const float* bc  = (const float*)d_in[6];
    const float* We0 = (const float*)d_in[7];
    const float* be0 = (const float*)d_in[8];
    const float* We1 = (const float*)d_in[9];
    const float* be1 = (const float*)d_in[10];
    const float* Wp  = (const float*)d_in[11];
    const float* bp  = (const float*)d_in[12];

    char* ws = (char*)d_ws;
    unsigned short* hbf    = (unsigned short*)(ws);                //  5,120,000
    float*          Afl    = (float*)(ws + 5120000);               // 10,240,000
    unsigned short* Bbf    = (unsigned short*)(ws + 15360000);     //  5,120,000
    int4*           es     = (int4*)(ws + 20480000);               // 20,480,000
    unsigned short* WcT    = (unsigned short*)(ws + 40960000);     //     81,920
    unsigned short* Wab0   = (unsigned short*)(ws + 41041920);     //     65,536
    unsigned short* Wab1   = (unsigned short*)(ws + 41107456);     //     65,536
    unsigned*       parent = (unsigned*)(ws + 41172992);           //      1,536
    unsigned*       hist   = (unsigned*)(ws + 41174528);           //     80,000
    unsigned*       cstart = (unsigned*)(ws + 41254528);           //     80,064
    unsigned*       cursor = (unsigned*)(ws + 41334592);           //     80,000
    unsigned*       qctr   = (unsigned*)(ws + 41414592);           //          8

    const float* Wef0 = We0 + 256 * 128;   // [12][128] rows 256..267
    const float* Wef1 = We1 + 256 * 128;

    hipMemsetAsync(hist, 0, N_NODES * 4, stream);

    setup_kernel<<<2916, 256, 0, stream>>>(Wc, We0, We1, eidx, WcT, Wab0, Wab1, hist);
    scan_kernel<<<1, 1024, 0, stream>>>(hist, cursor, cstart, parent, qctr);
    scatter_kernel<<<2500, 256, 0, stream>>>(eidx, onehot, efeat, cursor, es);

    // child + layer-1 A|B fused (h never leaves LDS)
    child_ab<<<313, 256, 0, stream>>>(child_feats, child_exists, WcT, bc,
                                      Wab0, be0, Afl, Bbf, parent);

    // ---- layer 1 edges ----
    edge_pass<<<2048, 256, 0, stream>>>(Bbf, Afl, es, Wef0, cstart, hist,
                                        qctr + 0, hbf, parent + 128);

    // ---- layer 2 ----
    gemmAB<<<625, 256, 0, stream>>>(hbf, Wab1, be1, Afl, Bbf);
    edge_pass<<<2048, 256, 0, stream>>>(Bbf, Afl, es, Wef1, cstart, hist,
                                        qctr + 1, hbf, parent + 256);

    final_gemm<<<16, 256, 0, stream>>>((const float*)parent, Wp, bp, (float*)d_out);
}

// Round 15
// 262.667 us; speedup vs baseline: 2.1632x; 2.1632x over previous
//
#include <hip/hip_runtime.h>

// ---------------- problem constants ----------------
#define N_NODES   20000
#define N_EDGES   640000
#define CF        313      // FEAT + NUM_SEM
#define KC        320      // child K padded (313 -> 320), 10 ksteps
#define ROWB      640      // child LDS A-tile row stride bytes

typedef __attribute__((ext_vector_type(8))) short short8;
typedef __attribute__((ext_vector_type(4))) float f32x4;
typedef __attribute__((ext_vector_type(4))) unsigned short u16x4;
typedef float f32x4u __attribute__((ext_vector_type(4), aligned(4)));
typedef _Float16 h2 __attribute__((ext_vector_type(2)));

static __device__ __forceinline__ unsigned short f2bf(float f) {
    unsigned u = __float_as_uint(f);
    u = u + 0x7FFFu + ((u >> 16) & 1u);   // RNE
    return (unsigned short)(u >> 16);
}
static __device__ __forceinline__ int pkh(float a, float b) {
    h2 h; h.x = (_Float16)a; h.y = (_Float16)b;
    return __builtin_bit_cast(int, h);
}
static __device__ __forceinline__ h2 bch(int v) { return __builtin_bit_cast(h2, v); }
static __device__ __forceinline__ float dot2f(h2 a, h2 b, float c) {
    return __builtin_amdgcn_fdot2(a, b, c, false);   // v_dot2_f32_f16
}

// ---------------- fused setup: weight prep | edge hist ----------------
__global__ void setup_kernel(const float* __restrict__ Wc,
                             const float* __restrict__ We0,
                             const float* __restrict__ We1,
                             const int* __restrict__ eidx,
                             unsigned short* __restrict__ WcT,
                             unsigned short* __restrict__ Wab0,
                             unsigned short* __restrict__ Wab1,
                             unsigned* __restrict__ hist) {
    const int b = blockIdx.x, tid = threadIdx.x;
    if (b < 416) {
        int g = b * 256 + tid;                    // 106496 = 416*256
        if (g < 128 * KC) {
            int n = g / KC, k = g % KC;
            WcT[g] = f2bf(k < CF ? Wc[k * 128 + n] : 0.f);
        } else if (g < 128 * KC + 32768) {
            int h = g - 128 * KC;
            int n = h >> 7, k = h & 127;
            Wab0[h] = f2bf(n < 128 ? We0[k * 128 + n] : We0[(128 + k) * 128 + (n - 128)]);
        } else {
            int h = g - 128 * KC - 32768;
            int n = h >> 7, k = h & 127;
            Wab1[h] = f2bf(n < 128 ? We1[k * 128 + n] : We1[(128 + k) * 128 + (n - 128)]);
        }
    } else {
        int e = (b - 416) * 256 + tid;
        if (e < N_EDGES) atomicAdd(hist + eidx[2 * e], 1u);
    }
}

// ---------------- scan (exclusive prefix over 20000 counts) + parent zero ---
__global__ void scan_kernel(const unsigned* __restrict__ hist,
                            unsigned* __restrict__ cursor,
                            unsigned* __restrict__ cstart,
                            unsigned* __restrict__ parent) {
    __shared__ unsigned part[1024];
    int t = threadIdx.x;
    if (t < 384) parent[t] = 0;                   // runs before child_ab
    unsigned loc[20];
    unsigned s = 0;
    int base = t * 20;
    if (t < 1000) {
        #pragma unroll
        for (int i = 0; i < 20; ++i) { loc[i] = hist[base + i]; s += loc[i]; }
    }
    part[t] = s;
    __syncthreads();
    for (int off = 1; off < 1024; off <<= 1) {
        unsigned u = (t >= off) ? part[t - off] : 0u;
        __syncthreads();
        part[t] += u;
        __syncthreads();
    }
    if (t < 1000) {
        unsigned run = part[t] - s;
        #pragma unroll
        for (int i = 0; i < 20; ++i) {
            cursor[base + i] = run;
            cstart[base + i] = run;
            run += loc[i];
        }
    }
}

// 32B record per sorted edge: {dst, ef01, ef23, ef45, ef67, ef89, efAB, pad}
__global__ void scatter_kernel(const int* __restrict__ eidx,
                               const float* __restrict__ onehot,
                               const float* __restrict__ efeat,
                               unsigned* __restrict__ cursor,
                               int4* __restrict__ es) {
    int e = blockIdx.x * 256 + threadIdx.x;
    if (e >= N_EDGES) return;
    int2 sd = ((const int2*)eidx)[e];
    unsigned pos = atomicAdd(cursor + sd.x, 1u);
    float4 oh = *(const float4*)(onehot + 4 * (size_t)e);
    float4 ea = *(const float4*)(efeat + 8 * (size_t)e);
    float4 eb = *(const float4*)(efeat + 8 * (size_t)e + 4);
    int4 w0, w1;
    w0.x = sd.y;
    w0.y = pkh(oh.x, oh.y); w0.z = pkh(oh.z, oh.w); w0.w = pkh(ea.x, ea.y);
    w1.x = pkh(ea.z, ea.w); w1.y = pkh(eb.x, eb.y); w1.z = pkh(eb.z, eb.w);
    w1.w = 0;
    es[2 * (size_t)pos]     = w0;
    es[2 * (size_t)pos + 1] = w1;
}

// ---------------- fused child encoder + A|B GEMM ----------------------------
// phase 1: h = relu(cf @ Wc + bc) * exists  (h kept in LDS, colmax -> parent)
// phase 2: A = h@Wsrc + be (f32), B = h@Wdst (bf16) from the same 64-row tile
__global__ __launch_bounds__(256)
void child_ab(const float* __restrict__ cf,             // [20000][313] f32
              const float* __restrict__ exists,
              const unsigned short* __restrict__ WcT,   // [128][320] bf16
              const float* __restrict__ bc,
              const unsigned short* __restrict__ Wab,   // [256][128] bf16
              const float* __restrict__ be,
              float* __restrict__ Afl,                  // [20000][128] f32
              unsigned short* __restrict__ Bbf,         // [20000][128] bf16
              unsigned int* __restrict__ pmax) {        // [128] colmax
    __shared__ __align__(16) unsigned char Alds[64 * ROWB];   // 40 KB
    __shared__ __align__(16) unsigned char Hlds[64 * 256];    // 16 KB

    const int tid  = threadIdx.x;
    const int lane = tid & 63;
    const int wave = tid >> 6;
    const int row0 = blockIdx.x * 64;

    // ======== phase 1: child ========
    const int n0c = wave * 32;
    short8 bfrag[10][2];
    {
        int col  = n0c + (lane & 15);
        int krow = (lane >> 4) * 8;
        #pragma unroll
        for (int ks = 0; ks < 10; ++ks)
            #pragma unroll
            for (int nt = 0; nt < 2; ++nt)
                bfrag[ks][nt] = *(const short8*)(WcT + (col + nt * 16) * KC + ks * 32 + krow);
    }
    float bvc[2];
    bvc[0] = bc[n0c + (lane & 15)];
    bvc[1] = bc[n0c + 16 + (lane & 15)];

    {   // stage cf tile (vectorized 4B-aligned loads)
        int r = tid >> 2, p = tid & 3;
        int node = row0 + r;
        bool valid = node < N_NODES;
        const float* g = cf + (size_t)node * CF;
        unsigned rbase = r * ROWB;
        unsigned sw = (r & 7) << 4;
        #pragma unroll
        for (int i = 0; i < 10; ++i) {
            int c = p + i * 4;                 // chunk 0..39, 8 bf16 each
            short8 v = {};
            if (valid) {
                if (c < 39) {
                    f32x4u a0 = *(const f32x4u*)(g + c * 8);
                    f32x4u a1 = *(const f32x4u*)(g + c * 8 + 4);
                    v[0] = (short)f2bf(a0.x); v[1] = (short)f2bf(a0.y);
                    v[2] = (short)f2bf(a0.z); v[3] = (short)f2bf(a0.w);
                    v[4] = (short)f2bf(a1.x); v[5] = (short)f2bf(a1.y);
                    v[6] = (short)f2bf(a1.z); v[7] = (short)f2bf(a1.w);
                } else {
                    v[0] = (short)f2bf(g[312]);   // k=312 only (313..319 pad)
                }
            }
            *(short8*)(Alds + ((rbase + c * 16) ^ sw)) = v;
        }
    }
    __syncthreads();

    f32x4 acc[4][2] = {};
    {
        int arow = lane & 15;
        unsigned kb = (lane >> 4) * 16;
        #pragma unroll
        for (int ks = 0; ks < 10; ++ks)
            #pragma unroll
            for (int mt = 0; mt < 4; ++mt) {
                int row = mt * 16 + arow;
                short8 a = *(const short8*)(Alds + (((unsigned)row * ROWB + ks * 64 + kb) ^ ((row & 7) << 4)));
                acc[mt][0] = __builtin_amdgcn_mfma_f32_16x16x32_bf16(a, bfrag[ks][0], acc[mt][0], 0, 0, 0);
                acc[mt][1] = __builtin_amdgcn_mfma_f32_16x16x32_bf16(a, bfrag[ks][1], acc[mt][1], 0, 0, 0);
            }
    }

    {   // epilogue: h -> Hlds (swizzled bf16) + column max
        int rb = (lane >> 4) * 4;
        #pragma unroll
        for (int nt = 0; nt < 2; ++nt) {
            int col = n0c + nt * 16 + (lane & 15);
            float m = 0.f;
            #pragma unroll
            for (int mt = 0; mt < 4; ++mt)
                #pragma unroll
                for (int j = 0; j < 4; ++j) {
                    int r = mt * 16 + rb + j;
                    int node = row0 + r;
                    float v = 0.f;
                    if (node < N_NODES)
                        v = fmaxf(acc[mt][nt][j] + bvc[nt], 0.f) * exists[node];
                    *(unsigned short*)(Hlds + (((unsigned)r * 256 + col * 2) ^ ((r & 7) << 4))) = f2bf(v);
                    m = fmaxf(m, v);
                }
            m = fmaxf(m, __shfl_xor(m, 16));
            m = fmaxf(m, __shfl_xor(m, 32));
            if ((lane >> 4) == 0)
                atomicMax(pmax + col, __float_as_uint(m));
        }
    }
    __syncthreads();

    // ======== phase 2: A|B from Hlds ========
    const int n0 = wave * 64;
    const int krow = (lane >> 4) * 8;
    short8 bfrag2[4][4];
    {
        int colb = n0 + (lane & 15);
        #pragma unroll
        for (int ks = 0; ks < 4; ++ks)
            #pragma unroll
            for (int nt = 0; nt < 4; ++nt)
                bfrag2[ks][nt] = *(const short8*)(Wab + (colb + nt * 16) * 128 + ks * 32 + krow);
    }

    f32x4 acc2[4][4] = {};
    #pragma unroll
    for (int ks = 0; ks < 4; ++ks)
        #pragma unroll
        for (int mt = 0; mt < 4; ++mt) {
            int r = mt * 16 + (lane & 15);
            short8 a = *(const short8*)(Hlds + (((unsigned)r * 256 + ks * 64 + krow * 2) ^ ((r & 7) << 4)));
            #pragma unroll
            for (int nt = 0; nt < 4; ++nt)
                acc2[mt][nt] = __builtin_amdgcn_mfma_f32_16x16x32_bf16(a, bfrag2[ks][nt], acc2[mt][nt], 0, 0, 0);
        }

    {
        int rb = (lane >> 4) * 4;
        #pragma unroll
        for (int nt = 0; nt < 4; ++nt) {
            int col = n0 + nt * 16 + (lane & 15);        // 0..255
            float badd = (col < 128) ? be[col] : 0.f;
            #pragma unroll
            for (int mt = 0; mt < 4; ++mt)
                #pragma unroll
                for (int j = 0; j < 4; ++j) {
                    int row = row0 + mt * 16 + rb + j;
                    if (row < N_NODES) {
                        float v = acc2[mt][nt][j] + badd;
                        if (col < 128) Afl[(size_t)row * 128 + col] = v;
                        else           Bbf[(size_t)row * 128 + col - 128] = f2bf(v);
                    }
                }
        }
    }
}

// ---------------- A|B node GEMM (layer 2): 32-row tiles, 625 blocks ---------
__global__ __launch_bounds__(256)
void gemmAB(const unsigned short* __restrict__ hbf,
            const unsigned short* __restrict__ WT,    // [256][128] bf16
            const float* __restrict__ bias,
            float* __restrict__ Afl,
            unsigned short* __restrict__ Bbf) {
    const int tid  = threadIdx.x;
    const int lane = tid & 63;
    const int wave = tid >> 6;
    const int n0   = wave * 64;
    const int row0 = blockIdx.x * 32;       // 625 * 32 = 20000 exactly
    const int krow = (lane >> 4) * 8;

    short8 bfrag[4][4];
    {
        int colb = n0 + (lane & 15);
        #pragma unroll
        for (int ks = 0; ks < 4; ++ks)
            #pragma unroll
            for (int nt = 0; nt < 4; ++nt)
                bfrag[ks][nt] = *(const short8*)(WT + (colb + nt * 16) * 128 + ks * 32 + krow);
    }

    f32x4 acc[2][4] = {};
    #pragma unroll
    for (int ks = 0; ks < 4; ++ks)
        #pragma unroll
        for (int mt = 0; mt < 2; ++mt) {
            int row = row0 + mt * 16 + (lane & 15);
            short8 a = *(const short8*)(hbf + (size_t)row * 128 + ks * 32 + krow);
            #pragma unroll
            for (int nt = 0; nt < 4; ++nt)
                acc[mt][nt] = __builtin_amdgcn_mfma_f32_16x16x32_bf16(a, bfrag[ks][nt], acc[mt][nt], 0, 0, 0);
        }

    {
        int rb = (lane >> 4) * 4;
        #pragma unroll
        for (int nt = 0; nt < 4; ++nt) {
            int col = n0 + nt * 16 + (lane & 15);
            float badd = (col < 128) ? bias[col] : 0.f;
            #pragma unroll
            for (int mt = 0; mt < 2; ++mt)
                #pragma unroll
                for (int j = 0; j < 4; ++j) {
                    int row = row0 + mt * 16 + rb + j;
                    float v = acc[mt][nt][j] + badd;
                    if (col < 128) Afl[(size_t)row * 128 + col] = v;
                    else           Bbf[(size_t)row * 128 + col - 128] = f2bf(v);
                }
        }
    }
}

// ---------------- edge pass (r7/r10-exact): per-src groups, static rings ----
// h[s] = relu(A[s] + max_e(B[dst_e] + ef_e @ Wef)). One 32-lane group per src.
__global__ __launch_bounds__(256, 3)
void edge_pass(const unsigned short* __restrict__ Bbf,  // [20000][128] bf16
               const float* __restrict__ Afl,           // [20000][128] f32
               const int4* __restrict__ es,             // 2 int4 per sorted edge
               const float* __restrict__ Wef,           // [12][128] f32
               const unsigned* __restrict__ cstart,     // [20000] seg start
               const unsigned* __restrict__ hist,       // [20000] seg count
               unsigned short* __restrict__ hbf,        // out h bf16
               unsigned* __restrict__ pslice) {         // [128] colmax f32-bits
    __shared__ unsigned cmax[128];
    const int tid = threadIdx.x;
    if (tid < 128) cmax[tid] = 0;
    __syncthreads();

    const int s  = blockIdx.x * 8 + (tid >> 5);   // 2500*8 = 20000
    const int c0 = (tid & 31) * 4;

    float4 a = *(const float4*)(Afl + (size_t)s * 128 + c0);   // epilogue operand

    h2 wf[6][4];
    #pragma unroll
    for (int kp = 0; kp < 6; ++kp)
        #pragma unroll
        for (int j = 0; j < 4; ++j) {
            h2 w;
            w.x = (_Float16)Wef[(2 * kp) * 128 + c0 + j];
            w.y = (_Float16)Wef[(2 * kp + 1) * 128 + c0 + j];
            wf[kp][j] = w;
        }

    float m0 = -1e30f, m1 = -1e30f, m2 = -1e30f, m3 = -1e30f;
    const unsigned cnt = hist[s];
    if (cnt) {
        const unsigned last = cnt - 1;
        const unsigned cb = cstart[s] * 32u;          // byte offset into es
        const char* esb = (const char*)es;
        const unsigned short* bbase = Bbf + c0;

        unsigned dstv[12];
        int4 ra[3], rb[3];
        u16x4 bv[6];

        #pragma unroll
        for (int k = 0; k < 12; ++k)
            dstv[k] = *(const unsigned*)(esb + cb + min((unsigned)k, last) * 32u);
        #pragma unroll
        for (int k = 0; k < 3; ++k) {
            const int4* q = (const int4*)(esb + cb + min((unsigned)k, last) * 32u);
            ra[k] = q[0]; rb[k] = q[1];
        }
        #pragma unroll
        for (int k = 0; k < 6; ++k)
            bv[k] = *(const u16x4*)(bbase + (size_t)dstv[k] * 128);

        const unsigned niter = (cnt + 11) / 12;
        for (unsigned it = 0; it < niter; ++it) {
            const unsigned jb = it * 12;
            #pragma unroll
            for (int u = 0; u < 12; ++u) {
                int4 RA = ra[u % 3], RB = rb[u % 3];
                u16x4 B = bv[u % 6];
                h2 e0 = bch(RA.y), e1 = bch(RA.z), e2 = bch(RA.w);
                h2 e3 = bch(RB.x), e4 = bch(RB.y), e5 = bch(RB.z);

                float x0 = __uint_as_float(((unsigned)(unsigned short)B[0]) << 16);
                float x1 = __uint_as_float(((unsigned)(unsigned short)B[1]) << 16);
                float x2 = __uint_as_float(((unsigned)(unsigned short)B[2]) << 16);
                float x3 = __uint_as_float(((unsigned)(unsigned short)B[3]) << 16);
                x0 = dot2f(e0, wf[0][0], x0); x1 = dot2f(e0, wf[0][1], x1);
                x2 = dot2f(e0, wf[0][2], x2); x3 = dot2f(e0, wf[0][3], x3);
                x0 = dot2f(e1, wf[1][0], x0); x1 = dot2f(e1, wf[1][1], x1);
                x2 = dot2f(e1, wf[1][2], x2); x3 = dot2f(e1, wf[1][3], x3);
                x0 = dot2f(e2, wf[2][0], x0); x1 = dot2f(e2, wf[2][1], x1);
                x2 = dot2f(e2, wf[2][2], x2); x3 = dot2f(e2, wf[2][3], x3);
                x0 = dot2f(e3, wf[3][0], x0); x1 = dot2f(e3, wf[3][1], x1);
                x2 = dot2f(e3, wf[3][2], x2); x3 = dot2f(e3, wf[3][3], x3);
                x0 = dot2f(e4, wf[4][0], x0); x1 = dot2f(e4, wf[4][1], x1);
                x2 = dot2f(e4, wf[4][2], x2); x3 = dot2f(e4, wf[4][3], x3);
                x0 = dot2f(e5, wf[5][0], x0); x1 = dot2f(e5, wf[5][1], x1);
                x2 = dot2f(e5, wf[5][2], x2); x3 = dot2f(e5, wf[5][3], x3);
                m0 = fmaxf(m0, x0); m1 = fmaxf(m1, x1);
                m2 = fmaxf(m2, x2); m3 = fmaxf(m3, x3);

                // ---- ring refills (all clamped; duplicates are idempotent) ----
                unsigned jd = min(jb + u + 12u, last);
                dstv[u] = *(const unsigned*)(esb + cb + jd * 32u);
                unsigned jr = min(jb + u + 3u, last);
                const int4* q = (const int4*)(esb + cb + jr * 32u);
                ra[u % 3] = q[0]; rb[u % 3] = q[1];
                bv[u % 6] = *(const u16x4*)(bbase + (size_t)dstv[(u + 6) % 12] * 128);
            }
        }
    }

    float h0 = fmaxf(a.x + m0, 0.f), h1 = fmaxf(a.y + m1, 0.f);
    float h2v = fmaxf(a.z + m2, 0.f), h3 = fmaxf(a.w + m3, 0.f);

    unsigned lo = (unsigned)f2bf(h0) | ((unsigned)f2bf(h1) << 16);
    unsigned hi = (unsigned)f2bf(h2v) | ((unsigned)f2bf(h3) << 16);
    *(uint2*)(hbf + (size_t)s * 128 + c0) = make_uint2(lo, hi);

    // colmax: reduce the two srcs of this wave, then LDS, then global
    float g0 = fmaxf(h0, __shfl_xor(h0, 32));
    float g1 = fmaxf(h1, __shfl_xor(h1, 32));
    float g2 = fmaxf(h2v, __shfl_xor(h2v, 32));
    float g3 = fmaxf(h3, __shfl_xor(h3, 32));
    if ((tid & 63) < 32) {
        atomicMax(&cmax[c0],     __float_as_uint(g0));
        atomicMax(&cmax[c0 + 1], __float_as_uint(g1));
        atomicMax(&cmax[c0 + 2], __float_as_uint(g2));
        atomicMax(&cmax[c0 + 3], __float_as_uint(g3));
    }
    __syncthreads();
    if (tid < 128) atomicMax(pslice + tid, cmax[tid]);
}

// ---------------- final: out = relu(parent @ Wp + bp), 16 blocks ------------
__global__ void final_gemm(const float* __restrict__ parent,
                           const float* __restrict__ Wp,
                           const float* __restrict__ bp,
                           float* __restrict__ out) {
    __shared__ float p[384];
    __shared__ float red[256];
    int t = threadIdx.x;
    for (int i = t; i < 384; i += 256) p[i] = parent[i];
    __syncthreads();
    int col = blockIdx.x * 16 + (t & 15);       // 16 blocks x 16 cols
    int kc  = t >> 4;                           // 16 k-slices x 24
    float s = 0.f;
    for (int k = kc * 24; k < kc * 24 + 24; ++k) s += p[k] * Wp[k * 256 + col];
    red[t] = s;
    __syncthreads();
    #pragma unroll
    for (int off = 8; off >= 1; off >>= 1) {
        if (kc < off) red[t] += red[t + off * 16];
        __syncthreads();
    }
    if (t < 16) out[col] = fmaxf(red[t] + bp[col], 0.f);
}

// ---------------- launch ----------------------------------------------------
extern "C" void kernel_launch(void* const* d_in, const int* in_sizes, int n_in,
                              void* d_out, int out_size, void* d_ws, size_t ws_size,
                              hipStream_t stream) {
    const float* child_feats  = (const float*)d_in[0];
    const float* child_exists = (const float*)d_in[1];
    const float* onehot       = (const float*)d_in[2];
    const float* efeat        = (const float*)d_in[3];
    const int*   eidx         = (const int*)d_in[4];
    const float* Wc  = (const float*)d_in[5];
    const float* bc  = (const float*)d_in[6];
    const float* We0 = (const float*)d_in[7];
    const float* be0 = (const float*)d_in[8];
    const float* We1 = (const float*)d_in[9];
    const float* be1 = (const float*)d_in[10];
    const float* Wp  = (const float*)d_in[11];
    const float* bp  = (const float*)d_in[12];

    char* ws = (char*)d_ws;
    unsigned short* hbf    = (unsigned short*)(ws);                //  5,120,000
    float*          Afl    = (float*)(ws + 5120000);               // 10,240,000
    unsigned short* Bbf    = (unsigned short*)(ws + 15360000);     //  5,120,000
    int4*           es     = (int4*)(ws + 20480000);               // 20,480,000
    unsigned short* WcT    = (unsigned short*)(ws + 40960000);     //     81,920
    unsigned short* Wab0   = (unsigned short*)(ws + 41041920);     //     65,536
    unsigned short* Wab1   = (unsigned short*)(ws + 41107456);     //     65,536
    unsigned*       parent = (unsigned*)(ws + 41172992);           //      1,536
    unsigned*       hist   = (unsigned*)(ws + 41174528);           //     80,000
    unsigned*       cstart = (unsigned*)(ws + 41254528);           //     80,064
    unsigned*       cursor = (unsigned*)(ws + 41334592);           //     80,000

    const float* Wef0 = We0 + 256 * 128;   // [12][128] rows 256..267
    const float* Wef1 = We1 + 256 * 128;

    hipMemsetAsync(hist, 0, N_NODES * 4, stream);

    setup_kernel<<<2916, 256, 0, stream>>>(Wc, We0, We1, eidx, WcT, Wab0, Wab1, hist);
    scan_kernel<<<1, 1024, 0, stream>>>(hist, cursor, cstart, parent);
    scatter_kernel<<<2500, 256, 0, stream>>>(eidx, onehot, efeat, cursor, es);

    // child + layer-1 A|B fused (h never leaves LDS)
    child_ab<<<313, 256, 0, stream>>>(child_feats, child_exists, WcT, bc,
                                      Wab0, be0, Afl, Bbf, parent);

    // ---- layer 1 edges ----
    edge_pass<<<2500, 256, 0, stream>>>(Bbf, Afl, es, Wef0, cstart, hist, hbf, parent + 128);

    // ---- layer 2 ----
    gemmAB<<<625, 256, 0, stream>>>(hbf, Wab1, be1, Afl, Bbf);
    edge_pass<<<2500, 256, 0, stream>>>(Bbf, Afl, es, Wef1, cstart, hist, hbf, parent + 256);

    final_gemm<<<16, 256, 0, stream>>>((const float*)parent, Wp, bp, (float*)d_out);
}